// Round 9
// baseline (574.423 us; speedup 1.0000x reference)
//
#include <hip/hip_runtime.h>
#include <math.h>

#define D_MODEL 768
#define HEADS   8
#define HDIM    96
#define SEQ     49
#define KQ      100
#define NB      128
#define FDIM    2048
#define FFD     2048
#define GRP     10
#define NCLS    1000

typedef unsigned short ushort_t;
typedef unsigned int uint_t;
typedef __attribute__((ext_vector_type(8))) short short8;
typedef __attribute__((ext_vector_type(4))) float f32x4;

// ---------------------------------------------------------------------------
// bf16 helpers (RNE rounding)
// ---------------------------------------------------------------------------
__device__ __forceinline__ float bf2f(ushort_t u) {
    uint_t x = ((uint_t)u) << 16;
    return __uint_as_float(x);
}
__device__ __forceinline__ ushort_t f2bf(float f) {
    uint_t x = __float_as_uint(f);
    x += 0x7fffu + ((x >> 16) & 1u);
    return (ushort_t)(x >> 16);
}

// async global->LDS, 16 bytes per lane (lds dest = wave-uniform base + lane*16)
__device__ __forceinline__ void gld_lds16(const void* g, void* l) {
    __builtin_amdgcn_global_load_lds(
        (const __attribute__((address_space(1))) unsigned int*)g,
        (__attribute__((address_space(3))) unsigned int*)l, 16, 0, 0);
}

// raw s_waitcnt imm (gfx9 encoding): vmcnt[3:0]+[15:14], expcnt[6:4]=7 (off),
// lgkmcnt[11:8]=15 (off)
#define WAITCNT_VM(N) (0x0F70 | ((N) & 15) | ((((N) >> 4) & 3) << 14))

// ---------------------------------------------------------------------------
// bf16 MFMA GEMM, BK=64, LDS XOR-swizzle (conflict-free, R6), XCD-aware block
// swizzle (R8), and NOW (R9) a DOUBLE-BUFFERED K-loop with raw s_barrier +
// partial vmcnt waits: next tile's global_load_lds stay IN FLIGHT across the
// barrier (AITER / m139 pattern) instead of the __syncthreads vmcnt(0) drain.
//   issue(0->buf0)
//   for k: s_barrier; issue(k+1 -> buf[(k+1)&1]);
//          s_waitcnt vmcnt(NCH); s_barrier; compute(buf[k&1])
// Barrier 1 = write-after-read guard (buf parity 2-iter reuse); barrier 2 =
// cross-wave visibility of iter-k staging (vmcnt is per-wave).
// A: [M][K] bf16 row-major.  Bt: [N][K] bf16 row-major.
// Block tile: (MT*32) x 128, 256 thr = 4 waves (2x2), wave = (MT*16)x64.
// K%64==0.  Split-N: cols < nsplit -> C/bias else C2/bias2 (nsplit%128==0).
// Epilogue residual: rmode 0=none, 1=+resid[row][col], 2=+resid[row%KQ][col].
// ---------------------------------------------------------------------------
template <int MT>
__global__ __launch_bounds__(256, 4) void gemm_bf16(
    const ushort_t* __restrict__ A, const ushort_t* __restrict__ Bt,
    const float* __restrict__ bias, const float* __restrict__ bias2,
    ushort_t* __restrict__ C, ushort_t* __restrict__ C2,
    int M, int N, int K, int nsplit, int relu, float scale,
    const ushort_t* __restrict__ resid, int rmode)
{
    constexpr int BM   = MT * 32;          // block rows
    constexpr int ACH  = MT * 4;           // A chunks (8 rows x 64k each)
    constexpr int NCH  = (ACH + 16) / 4;   // staging chunks per wave
    constexpr int BUFE = (BM + 128) * 64;  // elems per buffer

    __shared__ ushort_t smem[2 * BUFE];    // [buf][A(BM*64) | B(128*64)]

    const int tid  = threadIdx.x;
    const int w    = tid >> 6;
    const int lane = tid & 63;
    const int quad = lane >> 4;
    const int l16  = lane & 15;

    // ---- XCD-aware remap of (by,bx) -> (r,c) ----
    const int nx = gridDim.x, NY = gridDim.y;
    const int bid = blockIdx.y * nx + blockIdx.x;
    const int NYmain = NY & ~7;
    const int Tmain = NYmain * nx;
    int r, c;
    if (bid < Tmain) {
        const int grp = bid / (8 * nx);
        const int rem = bid - grp * 8 * nx;
        r = grp * 8 + (rem & 7);
        c = rem >> 3;
    } else {
        const int rem = bid - Tmain;
        r = NYmain + rem / nx;
        c = rem - (rem / nx) * nx;
    }
    const int rowBase = r * BM;
    const int nBase   = c * 128;
    const int wr = (w >> 1) * (MT * 16);
    const int wc = (w & 1) * 64;

    const float* biasb;
    ushort_t* Cb;
    int coff, ldcb;
    if (nBase < nsplit) { biasb = bias;  Cb = C;  coff = 0;      ldcb = nsplit; }
    else                { biasb = bias2; Cb = C2; coff = nsplit; ldcb = N - nsplit; }

    f32x4 acc[MT][4];
#pragma unroll
    for (int i = 0; i < MT; i++)
#pragma unroll
        for (int j = 0; j < 4; j++) acc[i][j] = (f32x4){0.f, 0.f, 0.f, 0.f};

    const int lrow = lane >> 3;
    const int ksub = ((lane & 7) ^ ((lane >> 3) & 7)) * 8;

    const ushort_t* gp[NCH];
    ushort_t* lp[NCH];                     // buf0 LDS dests
#pragma unroll
    for (int i = 0; i < NCH; i++) {
        int ch = w + 4 * i;
        if (ch < ACH) {
            int rr = min(rowBase + ch * 8 + lrow, M - 1);
            gp[i] = A + (size_t)rr * K + ksub;
            lp[i] = smem + ch * 512 + lane * 8;
        } else {
            int cb = ch - ACH;
            int rr = nBase + cb * 8 + lrow;
            gp[i] = Bt + (size_t)rr * K + ksub;
            lp[i] = smem + BM * 64 + cb * 512 + lane * 8;
        }
    }

    const int swl = l16 & 7;
    const int nit = K >> 6;

    // prologue: stage k=0 into buf0
#pragma unroll
    for (int i = 0; i < NCH; i++) gld_lds16(gp[i], lp[i]);

    for (int k = 0; k < nit; k++) {
        // barrier 1: everyone done READING buf[(k+1)&1] (from iter k-1)
        __builtin_amdgcn_s_barrier();

        if (k + 1 < nit) {
            const int koff = (k + 1) << 6;
            const int boff = ((k + 1) & 1) * BUFE;
#pragma unroll
            for (int i = 0; i < NCH; i++) gld_lds16(gp[i] + koff, lp[i] + boff);
            __builtin_amdgcn_s_waitcnt(WAITCNT_VM(NCH));  // iter-k landed; k+1 in flight
        } else {
            __builtin_amdgcn_s_waitcnt(WAITCNT_VM(0));
        }
        // barrier 2: all waves' iter-k staging visible
        __builtin_amdgcn_s_barrier();

        const ushort_t* As = smem + (k & 1) * BUFE;
        const ushort_t* Bs = As + BM * 64;

#pragma unroll
        for (int s = 0; s < 2; s++) {
            const int ks = ((4 * s + quad) ^ swl) * 8;
            short8 af[MT], bfr[4];
#pragma unroll
            for (int mt = 0; mt < MT; mt++)
                af[mt] = *(const short8*)(As + (wr + mt * 16 + l16) * 64 + ks);
#pragma unroll
            for (int nt = 0; nt < 4; nt++)
                bfr[nt] = *(const short8*)(Bs + (wc + nt * 16 + l16) * 64 + ks);
#pragma unroll
            for (int mt = 0; mt < MT; mt++)
#pragma unroll
                for (int nt = 0; nt < 4; nt++)
                    acc[mt][nt] = __builtin_amdgcn_mfma_f32_16x16x32_bf16(
                        af[mt], bfr[nt], acc[mt][nt], 0, 0, 0);
        }
    }

    // Epilogue: C/D layout col = lane&15, row = quad*4 + reg
#pragma unroll
    for (int nt = 0; nt < 4; nt++) {
        const int colg = nBase + wc + nt * 16 + l16;
        const int col  = colg - coff;
        const float bv = biasb[col];
#pragma unroll
        for (int mt = 0; mt < MT; mt++) {
#pragma unroll
            for (int rg = 0; rg < 4; rg++) {
                const int row = rowBase + wr + mt * 16 + quad * 4 + rg;
                if (row < M) {
                    float v = (acc[mt][nt][rg] + bv) * scale;
                    if (relu) v = fmaxf(v, 0.f);
                    if (rmode) {
                        int rrow = (rmode == 2) ? (row % KQ) : row;
                        v += bf2f(resid[(size_t)rrow * D_MODEL + col]);
                    }
                    Cb[(size_t)row * ldcb + col] = f2bf(v);
                }
            }
        }
    }
}

// ---------------------------------------------------------------------------
// Prep: ONE dispatch = 7 weight transposes (blocks 0..1727) + x convert
// (blocks 1728..2751).
// ---------------------------------------------------------------------------
__global__ __launch_bounds__(256) void prep_all(
    const float* __restrict__ We, const float* __restrict__ wq,
    const float* __restrict__ wk, const float* __restrict__ wv,
    const float* __restrict__ wo, const float* __restrict__ w1,
    const float* __restrict__ w2, const float* __restrict__ x,
    ushort_t* __restrict__ Wet, ushort_t* __restrict__ wqt,
    ushort_t* __restrict__ wkt, ushort_t* __restrict__ wvt,
    ushort_t* __restrict__ wot, ushort_t* __restrict__ w1t,
    ushort_t* __restrict__ w2t, ushort_t* __restrict__ xb)
{
    __shared__ __align__(16) char smem[25600];
    int t = blockIdx.x;
    if (t < 1728) {
        float* tile = (float*)smem;              // [64][65]
        const float* src; ushort_t* dst; int K, N, tx;
        if (t < 384)       {           src = We; dst = Wet; K = 2048; N = 768;  tx = 12; }
        else if (t < 528)  { t -= 384; src = wq; dst = wqt; K = 768;  N = 768;  tx = 12; }
        else if (t < 672)  { t -= 528; src = wk; dst = wkt; K = 768;  N = 768;  tx = 12; }
        else if (t < 816)  { t -= 672; src = wv; dst = wvt; K = 768;  N = 768;  tx = 12; }
        else if (t < 960)  { t -= 816; src = wo; dst = wot; K = 768;  N = 768;  tx = 12; }
        else if (t < 1344) { t -= 960; src = w1; dst = w1t; K = 768;  N = 2048; tx = 32; }
        else               { t -= 1344; src = w2; dst = w2t; K = 2048; N = 768; tx = 12; }
        const int n0 = (t % tx) * 64, k0 = (t / tx) * 64;
        const int tr = threadIdx.x >> 6, tc = threadIdx.x & 63;
#pragma unroll
        for (int i = 0; i < 16; i++) {
            int r = i * 4 + tr;
            tile[r * 65 + tc] = src[(size_t)(k0 + r) * N + n0 + tc];
        }
        __syncthreads();
#pragma unroll
        for (int i = 0; i < 16; i++) {
            int nr = i * 4 + tr;
            dst[(size_t)(n0 + nr) * K + k0 + tc] = f2bf(tile[tc * 65 + nr]);
        }
    } else {
        ushort_t* tile = (ushort_t*)smem;        // [256][50]
        int bx = t - 1728;
        const int b = bx >> 3, f0 = (bx & 7) * 256, tt = threadIdx.x;
        const float* src = x + ((size_t)b * FDIM + f0 + tt) * SEQ;
#pragma unroll
        for (int s = 0; s < SEQ; s++) tile[tt * 50 + s] = f2bf(src[s]);
        __syncthreads();
        for (int s = 0; s < SEQ; s++)
            xb[(size_t)(b * SEQ + s) * FDIM + f0 + tt] = tile[tt * 50 + s];
    }
}

// ---------------------------------------------------------------------------
// LayerNorm, wave-per-row (4 rows/block, shfl-only reduction, no LDS).
// ---------------------------------------------------------------------------
__global__ __launch_bounds__(256) void ln4(
    const void* __restrict__ in, int in_bf16,
    const float* __restrict__ g, const float* __restrict__ be,
    ushort_t* __restrict__ out, float pre_scale, int nrows)
{
    const int w = threadIdx.x >> 6, lane = threadIdx.x & 63;
    const int row = blockIdx.x * 4 + w;
    if (row >= nrows) return;

    float v[12];
    if (in_bf16) {
        const uint_t* p = (const uint_t*)in + (size_t)row * 384;
#pragma unroll
        for (int i = 0; i < 6; i++) {
            uint_t u = p[lane + i * 64];
            v[2 * i]     = bf2f((ushort_t)(u & 0xffff)) * pre_scale;
            v[2 * i + 1] = bf2f((ushort_t)(u >> 16)) * pre_scale;
        }
    } else {
        const float2* p = (const float2*)((const float*)in + (size_t)row * D_MODEL);
#pragma unroll
        for (int i = 0; i < 6; i++) {
            float2 t = p[lane + i * 64];
            v[2 * i] = t.x * pre_scale;
            v[2 * i + 1] = t.y * pre_scale;
        }
    }
    float s = 0.f;
#pragma unroll
    for (int i = 0; i < 12; i++) s += v[i];
#pragma unroll
    for (int off = 32; off > 0; off >>= 1) s += __shfl_xor(s, off);
    const float mean = s * (1.f / D_MODEL);
    float q = 0.f;
#pragma unroll
    for (int i = 0; i < 12; i++) { float d = v[i] - mean; q += d * d; }
#pragma unroll
    for (int off = 32; off > 0; off >>= 1) q += __shfl_xor(q, off);
    const float rstd = rsqrtf(q * (1.f / D_MODEL) + 1e-5f);

    const float2* g2 = (const float2*)g;
    const float2* b2 = (const float2*)be;
    uint_t* op = (uint_t*)out + (size_t)row * 384;
#pragma unroll
    for (int i = 0; i < 6; i++) {
        int j = lane + i * 64;
        float2 gg = g2[j], bb = b2[j];
        ushort_t lo = f2bf((v[2 * i] - mean) * rstd * gg.x + bb.x);
        ushort_t hi = f2bf((v[2 * i + 1] - mean) * rstd * gg.y + bb.y);
        op[j] = (uint_t)lo | ((uint_t)hi << 16);
    }
}

// ---------------------------------------------------------------------------
// MFMA cross-attention, one block per (b,h), 4 waves.  (unchanged — verified)
// ---------------------------------------------------------------------------
__global__ __launch_bounds__(256) void attn_mfma(
    const ushort_t* __restrict__ q, const ushort_t* __restrict__ k,
    const ushort_t* __restrict__ v, ushort_t* __restrict__ ctx)
{
    __shared__ ushort_t Pt[128][72];
    __shared__ ushort_t Vt[96][72];

    const int bh = blockIdx.x;
    const int b = bh >> 3, h = bh & 7;
    const int tid = threadIdx.x;
    const int w = tid >> 6, lane = tid & 63;
    const int quad = lane >> 4, l16 = lane & 15;
    const int mrow0 = 32 * w;

    for (int idx = tid; idx < 96 * 64; idx += 256) {
        int d = idx >> 6, s = idx & 63;
        ushort_t val = 0;
        if (s < SEQ) val = v[(size_t)(b * SEQ + s) * D_MODEL + h * HDIM + d];
        Vt[d][s] = val;
    }

    f32x4 accS[2][4];
#pragma unroll
    for (int i = 0; i < 2; i++)
#pragma unroll
        for (int j = 0; j < 4; j++) accS[i][j] = (f32x4){0.f, 0.f, 0.f, 0.f};

#pragma unroll
    for (int k0 = 0; k0 < HDIM; k0 += 32) {
        short8 af[2], bfr[4];
#pragma unroll
        for (int mt = 0; mt < 2; mt++) {
            int kq = min(mrow0 + mt * 16 + l16, KQ - 1);
            af[mt] = *(const short8*)(q + (size_t)kq * D_MODEL + h * HDIM + k0 + quad * 8);
        }
#pragma unroll
        for (int nt = 0; nt < 4; nt++) {
            int s = min(nt * 16 + l16, SEQ - 1);
            bfr[nt] = *(const short8*)(k + (size_t)(b * SEQ + s) * D_MODEL + h * HDIM + k0 + quad * 8);
        }
#pragma unroll
        for (int mt = 0; mt < 2; mt++)
#pragma unroll
            for (int nt = 0; nt < 4; nt++)
                accS[mt][nt] = __builtin_amdgcn_mfma_f32_16x16x32_bf16(
                    af[mt], bfr[nt], accS[mt][nt], 0, 0, 0);
    }

#pragma unroll
    for (int mt = 0; mt < 2; mt++) {
#pragma unroll
        for (int r = 0; r < 4; r++) {
            float vals[4];
            float vmax = -1e30f;
#pragma unroll
            for (int nt = 0; nt < 4; nt++) {
                vals[nt] = accS[mt][nt][r];
                if (nt * 16 + l16 < SEQ) vmax = fmaxf(vmax, vals[nt]);
            }
#pragma unroll
            for (int off = 1; off < 16; off <<= 1)
                vmax = fmaxf(vmax, __shfl_xor(vmax, off));
            float p[4], psum = 0.f;
#pragma unroll
            for (int nt = 0; nt < 4; nt++) {
                float e = (nt * 16 + l16 < SEQ) ? __expf(vals[nt] - vmax) : 0.f;
                p[nt] = e;
                psum += e;
            }
#pragma unroll
            for (int off = 1; off < 16; off <<= 1)
                psum += __shfl_xor(psum, off);
            const float inv = 1.f / psum;
            const int row = mrow0 + mt * 16 + quad * 4 + r;
#pragma unroll
            for (int nt = 0; nt < 4; nt++)
                Pt[row][nt * 16 + l16] = f2bf(p[nt] * inv);
        }
    }
    __syncthreads();

    f32x4 accO[2][6];
#pragma unroll
    for (int i = 0; i < 2; i++)
#pragma unroll
        for (int j = 0; j < 6; j++) accO[i][j] = (f32x4){0.f, 0.f, 0.f, 0.f};

#pragma unroll
    for (int k0 = 0; k0 < 64; k0 += 32) {
        short8 af[2], bfr[6];
#pragma unroll
        for (int mt = 0; mt < 2; mt++)
            af[mt] = *(const short8*)(&Pt[mrow0 + mt * 16 + l16][k0 + quad * 8]);
#pragma unroll
        for (int nt = 0; nt < 6; nt++)
            bfr[nt] = *(const short8*)(&Vt[nt * 16 + l16][k0 + quad * 8]);
#pragma unroll
        for (int mt = 0; mt < 2; mt++)
#pragma unroll
            for (int nt = 0; nt < 6; nt++)
                accO[mt][nt] = __builtin_amdgcn_mfma_f32_16x16x32_bf16(
                    af[mt], bfr[nt], accO[mt][nt], 0, 0, 0);
    }

#pragma unroll
    for (int mt = 0; mt < 2; mt++) {
#pragma unroll
        for (int r = 0; r < 4; r++) {
            const int kq = mrow0 + mt * 16 + quad * 4 + r;
            if (kq < KQ) {
                size_t oa = (size_t)(b * KQ + kq) * D_MODEL + h * HDIM;
#pragma unroll
                for (int nt = 0; nt < 6; nt++)
                    ctx[oa + nt * 16 + l16] = f2bf(accO[mt][nt][r]);
            }
        }
    }
}

// ---------------------------------------------------------------------------
// GroupFC + fused LN3.  Block = (bgroup of 8 batches, kq).  (verified R7)
// ---------------------------------------------------------------------------
__global__ __launch_bounds__(256) void groupfc3(
    const ushort_t* __restrict__ hb, const float* __restrict__ dp,
    const float* __restrict__ dbias, const float* __restrict__ g3,
    const float* __restrict__ be3, float* __restrict__ out)
{
    __shared__ float dps[D_MODEL * 11];   // [d][g] padded
    __shared__ float hsr[8][D_MODEL];
    __shared__ float gbs[2][D_MODEL];

    const int b0 = blockIdx.x * 8;
    const int kq = blockIdx.y;
    const int tid = threadIdx.x;

    for (int i = tid; i < D_MODEL * GRP; i += 256) {
        int d = i / GRP, g = i - d * GRP;
        dps[d * 11 + g] = dp[(size_t)kq * (D_MODEL * GRP) + i];
    }
    for (int i = tid; i < D_MODEL; i += 256) {
        gbs[0][i] = g3[i];
        gbs[1][i] = be3[i];
    }
#pragma unroll
    for (int bb = 0; bb < 8; bb++) {
#pragma unroll
        for (int i = 0; i < 3; i++) {
            int d = tid + i * 256;
            hsr[bb][d] = bf2f(hb[(size_t)((b0 + bb) * KQ + kq) * D_MODEL + d]);
        }
    }
    __syncthreads();

    const int w = tid >> 6, lane = tid & 63;

#pragma unroll
    for (int rr = 0; rr < 2; rr++) {
        const int r = w * 2 + rr;
        float v[12];
        float s = 0.f;
#pragma unroll
        for (int i = 0; i < 12; i++) { v[i] = hsr[r][lane + i * 64]; s += v[i]; }
#pragma unroll
        for (int off = 32; off > 0; off >>= 1) s += __shfl_xor(s, off);
        const float mean = s * (1.f / D_MODEL);
        float q = 0.f;
#pragma unroll
        for (int i = 0; i < 12; i++) { float d = v[i] - mean; q += d * d; }
#pragma unroll
        for (int off = 32; off > 0; off >>= 1) q += __shfl_xor(q, off);
        const float rstd = rsqrtf(q * (1.f / D_MODEL) + 1e-5f);
#pragma unroll
        for (int i = 0; i < 12; i++) {
            int d = lane + i * 64;
            hsr[r][d] = (v[i] - mean) * rstd * gbs[0][d] + gbs[1][d];
        }
    }
    __syncthreads();

    for (int item = w; item < 8 * GRP; item += 4) {
        int bb = item / GRP, g = item - bb * GRP;
        float a = 0.f;
#pragma unroll
        for (int i = 0; i < 12; i++) {
            int d = lane + i * 64;
            a = fmaf(hsr[bb][d], dps[d * 11 + g], a);
        }
#pragma unroll
        for (int off = 32; off > 0; off >>= 1) a += __shfl_down(a, off);
        if (lane == 0)
            out[(size_t)(b0 + bb) * NCLS + kq * GRP + g] = a + dbias[kq * GRP + g];
    }
}

// ---------------------------------------------------------------------------
extern "C" void kernel_launch(void* const* d_in, const int* in_sizes, int n_in,
                              void* d_out, int out_size, void* d_ws, size_t ws_size,
                              hipStream_t stream)
{
    const float* x   = (const float*)d_in[0];
    const float* We  = (const float*)d_in[1];
    const float* be_ = (const float*)d_in[2];
    const float* qe  = (const float*)d_in[3];
    const float* wq  = (const float*)d_in[4];
    const float* wk  = (const float*)d_in[5];
    const float* wv  = (const float*)d_in[6];
    const float* bq  = (const float*)d_in[7];
    const float* bk  = (const float*)d_in[8];
    const float* bv  = (const float*)d_in[9];
    const float* wo  = (const float*)d_in[10];
    const float* bo  = (const float*)d_in[11];
    const float* w1  = (const float*)d_in[12];
    const float* b1  = (const float*)d_in[13];
    const float* w2  = (const float*)d_in[14];
    const float* b2  = (const float*)d_in[15];
    const float* g1  = (const float*)d_in[16];
    const float* be1 = (const float*)d_in[17];
    const float* g2  = (const float*)d_in[18];
    const float* be2 = (const float*)d_in[19];
    const float* g3  = (const float*)d_in[20];
    const float* be3 = (const float*)d_in[21];
    const float* dp  = (const float*)d_in[22];
    const float* db  = (const float*)d_in[23];
    float* out = (float*)d_out;
    ushort_t* ws = (ushort_t*)d_ws;

    // Workspace (bf16 elems). Region A [0, 27,295,744) time-shared:
    //   phase1: xb | mem | kb | vb     phase2 (>= ffn1): ffh (26,214,400)
    ushort_t* xb  = ws;                      // 6272*2048 = 12,845,056
    ushort_t* mem = xb + 12845056;           // 6272*768  =  4,816,896
    ushort_t* kb  = mem + 4816896;
    ushort_t* vb  = kb + 4816896;
    ushort_t* ffh = ws;                      // 12800*2048 = 26,214,400 (phase2)
    ushort_t* rB  = ws + 27295744;
    ushort_t* Wet = rB;                      // 768*2048 = 1,572,864
    ushort_t* wqt = Wet + 1572864;           // 768*768  =   589,824
    ushort_t* wkt = wqt + 589824;            // wkt/wvt adjacent -> fused kv GEMM
    ushort_t* wvt = wkt + 589824;
    ushort_t* wot = wvt + 589824;
    ushort_t* w1t = wot + 589824;            // 2048*768 = 1,572,864
    ushort_t* w2t = w1t + 1572864;           // 768*2048 = 1,572,864
    ushort_t* tgt = w2t + 1572864;           // 100*768 = 76,800
    ushort_t* qb  = tgt + 76800;
    ushort_t* ctx = qb + 76800;              // 12800*768 = 9,830,400
    ushort_t* t2  = ctx + 9830400;
    ushort_t* hb  = t2 + 9830400;

    dim3 blk(256);
    const float qscale = 1.0f / sqrtf((float)HDIM);

    // 0. prep: 7 weight transposes + x convert, one dispatch
    prep_all<<<dim3(2752), blk, 0, stream>>>(We, wq, wk, wv, wo, w1, w2, x,
                                             Wet, wqt, wkt, wvt, wot, w1t, w2t, xb);

    // 1. mem = relu(xb @ We + b_embed)   [6272 x 768, K=2048]  MT=2 -> 588 blocks
    gemm_bf16<2><<<dim3(6, 98), blk, 0, stream>>>(xb, Wet, be_, be_, mem, mem,
                                                  6272, 768, 2048, 768, 1, 1.f, nullptr, 0);
    // 2. tgt = LN(2*qe)                  [100 rows]
    ln4<<<dim3(25), blk, 0, stream>>>(qe, 0, g1, be1, tgt, 2.0f, KQ);
    // 3. qb = (tgt@wq + bq)/sqrt(96)     [100 x 768, K=768]  MT=1 -> 24 blocks
    gemm_bf16<1><<<dim3(6, 4), blk, 0, stream>>>(tgt, wqt, bq, bq, qb, qb,
                                                 KQ, 768, 768, 768, 0, qscale, nullptr, 0);
    // 4. fused k|v                       [6272 x 1536, K=768], split at 768
    gemm_bf16<4><<<dim3(12, 49), blk, 0, stream>>>(mem, wkt, bk, bv, kb, vb,
                                                   6272, 1536, 768, 768, 0, 1.f, nullptr, 0);
    // 5. attention -> ctx
    attn_mfma<<<dim3(NB * HEADS), blk, 0, stream>>>(qb, kb, vb, ctx);
    // 6. t2 = ctx@wo + bo + bcast tgt    [12800 x 768, K=768]  (residual fused)
    gemm_bf16<4><<<dim3(6, 100), blk, 0, stream>>>(ctx, wot, bo, bo, t2, t2,
                                                   12800, 768, 768, 768, 0, 1.f, tgt, 2);
    // 7. t2 = LN(t2)                     [12800 rows]
    ln4<<<dim3(3200), blk, 0, stream>>>(t2, 1, g2, be2, t2, 1.0f, 12800);
    // 8. ffh = relu(t2@w1 + b1)          [12800 x 2048, K=768]
    gemm_bf16<4><<<dim3(16, 100), blk, 0, stream>>>(t2, w1t, b1, b1, ffh, ffh,
                                                    12800, 2048, 768, 2048, 1, 1.f, nullptr, 0);
    // 9. hb = ffh@w2 + b2 + t2           [12800 x 768, K=2048]  (residual fused)
    gemm_bf16<4><<<dim3(6, 100), blk, 0, stream>>>(ffh, w2t, b2, b2, hb, hb,
                                                   12800, 768, 2048, 768, 0, 1.f, t2, 1);
    // 10. GroupFC with fused LN3 -> out (fp32 logits)
    groupfc3<<<dim3(16, KQ), blk, 0, stream>>>(hb, dp, db, g3, be3, out);
}

// Round 10
// 483.708 us; speedup vs baseline: 1.1875x; 1.1875x over previous
//
#include <hip/hip_runtime.h>
#include <math.h>

#define D_MODEL 768
#define HEADS   8
#define HDIM    96
#define SEQ     49
#define KQ      100
#define NB      128
#define FDIM    2048
#define FFD     2048
#define GRP     10
#define NCLS    1000

typedef unsigned short ushort_t;
typedef unsigned int uint_t;
typedef __attribute__((ext_vector_type(8))) short short8;
typedef __attribute__((ext_vector_type(4))) float f32x4;

// ---------------------------------------------------------------------------
// bf16 helpers (RNE rounding)
// ---------------------------------------------------------------------------
__device__ __forceinline__ float bf2f(ushort_t u) {
    uint_t x = ((uint_t)u) << 16;
    return __uint_as_float(x);
}
__device__ __forceinline__ ushort_t f2bf(float f) {
    uint_t x = __float_as_uint(f);
    x += 0x7fffu + ((x >> 16) & 1u);
    return (ushort_t)(x >> 16);
}

// async global->LDS, 16 bytes per lane (lds dest = wave-uniform base + lane*16)
__device__ __forceinline__ void gld_lds16(const void* g, void* l) {
    __builtin_amdgcn_global_load_lds(
        (const __attribute__((address_space(1))) unsigned int*)g,
        (__attribute__((address_space(3))) unsigned int*)l, 16, 0, 0);
}

// ---------------------------------------------------------------------------
// bf16 MFMA GEMM, BK=64, single-buffer (R8 structure — R9's dbuf regressed on
// occupancy), LDS XOR-swizzle (conflict-free, R6), XCD-aware block swizzle
// (R8: FETCH 190->79MB on ffn2).  R10: big GEMMs now run MT=2 (64-row tiles)
// -> 2x grid, 24KB LDS, ~4-5 blocks/CU: barrier drains hidden by TLP.
// A: [M][K] bf16 row-major.  Bt: [N][K] bf16 row-major.
// Block tile: (MT*32) x 128, 256 thr = 4 waves (2x2), wave = (MT*16)x64.
// K%64==0.  Split-N: cols < nsplit -> C/bias else C2/bias2 (nsplit%128==0).
// Epilogue residual: rmode 0=none, 1=+resid[row][col], 2=+resid[row%KQ][col].
// ---------------------------------------------------------------------------
template <int MT>
__global__ __launch_bounds__(256, 4) void gemm_bf16(
    const ushort_t* __restrict__ A, const ushort_t* __restrict__ Bt,
    const float* __restrict__ bias, const float* __restrict__ bias2,
    ushort_t* __restrict__ C, ushort_t* __restrict__ C2,
    int M, int N, int K, int nsplit, int relu, float scale,
    const ushort_t* __restrict__ resid, int rmode)
{
    constexpr int BM  = MT * 32;        // block rows
    constexpr int ACH = MT * 4;         // A chunks (8 rows x 64k each)
    constexpr int NCH = (ACH + 16) / 4; // staging chunks per wave

    __shared__ ushort_t As[BM * 64];
    __shared__ ushort_t Bs[128 * 64];

    const int tid  = threadIdx.x;
    const int w    = tid >> 6;
    const int lane = tid & 63;
    const int quad = lane >> 4;
    const int l16  = lane & 15;

    // ---- XCD-aware remap of (by,bx) -> (r,c) ----
    const int nx = gridDim.x, NY = gridDim.y;
    const int bid = blockIdx.y * nx + blockIdx.x;
    const int NYmain = NY & ~7;
    const int Tmain = NYmain * nx;
    int r, c;
    if (bid < Tmain) {
        const int grp = bid / (8 * nx);
        const int rem = bid - grp * 8 * nx;
        r = grp * 8 + (rem & 7);
        c = rem >> 3;
    } else {
        const int rem = bid - Tmain;
        r = NYmain + rem / nx;
        c = rem - (rem / nx) * nx;
    }
    const int rowBase = r * BM;
    const int nBase   = c * 128;
    const int wr = (w >> 1) * (MT * 16);
    const int wc = (w & 1) * 64;

    const float* biasb;
    ushort_t* Cb;
    int coff, ldcb;
    if (nBase < nsplit) { biasb = bias;  Cb = C;  coff = 0;      ldcb = nsplit; }
    else                { biasb = bias2; Cb = C2; coff = nsplit; ldcb = N - nsplit; }

    f32x4 acc[MT][4];
#pragma unroll
    for (int i = 0; i < MT; i++)
#pragma unroll
        for (int j = 0; j < 4; j++) acc[i][j] = (f32x4){0.f, 0.f, 0.f, 0.f};

    const int lrow = lane >> 3;
    const int ksub = ((lane & 7) ^ ((lane >> 3) & 7)) * 8;

    const ushort_t* gp[NCH];
    ushort_t* lp[NCH];
#pragma unroll
    for (int i = 0; i < NCH; i++) {
        int ch = w + 4 * i;
        if (ch < ACH) {
            int rr = min(rowBase + ch * 8 + lrow, M - 1);
            gp[i] = A + (size_t)rr * K + ksub;
            lp[i] = As + ch * 512 + lane * 8;
        } else {
            int cb = ch - ACH;
            int rr = nBase + cb * 8 + lrow;
            gp[i] = Bt + (size_t)rr * K + ksub;
            lp[i] = Bs + cb * 512 + lane * 8;
        }
    }

    const int swl = l16 & 7;

    for (int k0 = 0; k0 < K; k0 += 64) {
#pragma unroll
        for (int i = 0; i < NCH; i++) gld_lds16(gp[i] + k0, lp[i]);
        __syncthreads();

#pragma unroll
        for (int s = 0; s < 2; s++) {
            const int ks = ((4 * s + quad) ^ swl) * 8;
            short8 af[MT], bfr[4];
#pragma unroll
            for (int mt = 0; mt < MT; mt++)
                af[mt] = *(const short8*)(As + (wr + mt * 16 + l16) * 64 + ks);
#pragma unroll
            for (int nt = 0; nt < 4; nt++)
                bfr[nt] = *(const short8*)(Bs + (wc + nt * 16 + l16) * 64 + ks);
#pragma unroll
            for (int mt = 0; mt < MT; mt++)
#pragma unroll
                for (int nt = 0; nt < 4; nt++)
                    acc[mt][nt] = __builtin_amdgcn_mfma_f32_16x16x32_bf16(
                        af[mt], bfr[nt], acc[mt][nt], 0, 0, 0);
        }
        __syncthreads();
    }

    // Epilogue: C/D layout col = lane&15, row = quad*4 + reg
#pragma unroll
    for (int nt = 0; nt < 4; nt++) {
        const int colg = nBase + wc + nt * 16 + l16;
        const int col  = colg - coff;
        const float bv = biasb[col];
#pragma unroll
        for (int mt = 0; mt < MT; mt++) {
#pragma unroll
            for (int rg = 0; rg < 4; rg++) {
                const int row = rowBase + wr + mt * 16 + quad * 4 + rg;
                if (row < M) {
                    float v = (acc[mt][nt][rg] + bv) * scale;
                    if (relu) v = fmaxf(v, 0.f);
                    if (rmode) {
                        int rrow = (rmode == 2) ? (row % KQ) : row;
                        v += bf2f(resid[(size_t)rrow * D_MODEL + col]);
                    }
                    Cb[(size_t)row * ldcb + col] = f2bf(v);
                }
            }
        }
    }
}

// ---------------------------------------------------------------------------
// Prep: ONE dispatch = 7 weight transposes (blocks 0..1727) + x convert
// (blocks 1728..2751).
// ---------------------------------------------------------------------------
__global__ __launch_bounds__(256) void prep_all(
    const float* __restrict__ We, const float* __restrict__ wq,
    const float* __restrict__ wk, const float* __restrict__ wv,
    const float* __restrict__ wo, const float* __restrict__ w1,
    const float* __restrict__ w2, const float* __restrict__ x,
    ushort_t* __restrict__ Wet, ushort_t* __restrict__ wqt,
    ushort_t* __restrict__ wkt, ushort_t* __restrict__ wvt,
    ushort_t* __restrict__ wot, ushort_t* __restrict__ w1t,
    ushort_t* __restrict__ w2t, ushort_t* __restrict__ xb)
{
    __shared__ __align__(16) char smem[25600];
    int t = blockIdx.x;
    if (t < 1728) {
        float* tile = (float*)smem;              // [64][65]
        const float* src; ushort_t* dst; int K, N, tx;
        if (t < 384)       {           src = We; dst = Wet; K = 2048; N = 768;  tx = 12; }
        else if (t < 528)  { t -= 384; src = wq; dst = wqt; K = 768;  N = 768;  tx = 12; }
        else if (t < 672)  { t -= 528; src = wk; dst = wkt; K = 768;  N = 768;  tx = 12; }
        else if (t < 816)  { t -= 672; src = wv; dst = wvt; K = 768;  N = 768;  tx = 12; }
        else if (t < 960)  { t -= 816; src = wo; dst = wot; K = 768;  N = 768;  tx = 12; }
        else if (t < 1344) { t -= 960; src = w1; dst = w1t; K = 768;  N = 2048; tx = 32; }
        else               { t -= 1344; src = w2; dst = w2t; K = 2048; N = 768; tx = 12; }
        const int n0 = (t % tx) * 64, k0 = (t / tx) * 64;
        const int tr = threadIdx.x >> 6, tc = threadIdx.x & 63;
#pragma unroll
        for (int i = 0; i < 16; i++) {
            int r = i * 4 + tr;
            tile[r * 65 + tc] = src[(size_t)(k0 + r) * N + n0 + tc];
        }
        __syncthreads();
#pragma unroll
        for (int i = 0; i < 16; i++) {
            int nr = i * 4 + tr;
            dst[(size_t)(n0 + nr) * K + k0 + tc] = f2bf(tile[tc * 65 + nr]);
        }
    } else {
        ushort_t* tile = (ushort_t*)smem;        // [256][50]
        int bx = t - 1728;
        const int b = bx >> 3, f0 = (bx & 7) * 256, tt = threadIdx.x;
        const float* src = x + ((size_t)b * FDIM + f0 + tt) * SEQ;
#pragma unroll
        for (int s = 0; s < SEQ; s++) tile[tt * 50 + s] = f2bf(src[s]);
        __syncthreads();
        for (int s = 0; s < SEQ; s++)
            xb[(size_t)(b * SEQ + s) * FDIM + f0 + tt] = tile[tt * 50 + s];
    }
}

// ---------------------------------------------------------------------------
// LayerNorm, wave-per-row (4 rows/block, shfl-only reduction, no LDS).
// ---------------------------------------------------------------------------
__global__ __launch_bounds__(256) void ln4(
    const void* __restrict__ in, int in_bf16,
    const float* __restrict__ g, const float* __restrict__ be,
    ushort_t* __restrict__ out, float pre_scale, int nrows)
{
    const int w = threadIdx.x >> 6, lane = threadIdx.x & 63;
    const int row = blockIdx.x * 4 + w;
    if (row >= nrows) return;

    float v[12];
    if (in_bf16) {
        const uint_t* p = (const uint_t*)in + (size_t)row * 384;
#pragma unroll
        for (int i = 0; i < 6; i++) {
            uint_t u = p[lane + i * 64];
            v[2 * i]     = bf2f((ushort_t)(u & 0xffff)) * pre_scale;
            v[2 * i + 1] = bf2f((ushort_t)(u >> 16)) * pre_scale;
        }
    } else {
        const float2* p = (const float2*)((const float*)in + (size_t)row * D_MODEL);
#pragma unroll
        for (int i = 0; i < 6; i++) {
            float2 t = p[lane + i * 64];
            v[2 * i] = t.x * pre_scale;
            v[2 * i + 1] = t.y * pre_scale;
        }
    }
    float s = 0.f;
#pragma unroll
    for (int i = 0; i < 12; i++) s += v[i];
#pragma unroll
    for (int off = 32; off > 0; off >>= 1) s += __shfl_xor(s, off);
    const float mean = s * (1.f / D_MODEL);
    float q = 0.f;
#pragma unroll
    for (int i = 0; i < 12; i++) { float d = v[i] - mean; q += d * d; }
#pragma unroll
    for (int off = 32; off > 0; off >>= 1) q += __shfl_xor(q, off);
    const float rstd = rsqrtf(q * (1.f / D_MODEL) + 1e-5f);

    const float2* g2 = (const float2*)g;
    const float2* b2 = (const float2*)be;
    uint_t* op = (uint_t*)out + (size_t)row * 384;
#pragma unroll
    for (int i = 0; i < 6; i++) {
        int j = lane + i * 64;
        float2 gg = g2[j], bb = b2[j];
        ushort_t lo = f2bf((v[2 * i] - mean) * rstd * gg.x + bb.x);
        ushort_t hi = f2bf((v[2 * i + 1] - mean) * rstd * gg.y + bb.y);
        op[j] = (uint_t)lo | ((uint_t)hi << 16);
    }
}

// ---------------------------------------------------------------------------
// MFMA cross-attention, one block per (b,h), 4 waves.  (unchanged — verified)
// ---------------------------------------------------------------------------
__global__ __launch_bounds__(256) void attn_mfma(
    const ushort_t* __restrict__ q, const ushort_t* __restrict__ k,
    const ushort_t* __restrict__ v, ushort_t* __restrict__ ctx)
{
    __shared__ ushort_t Pt[128][72];
    __shared__ ushort_t Vt[96][72];

    const int bh = blockIdx.x;
    const int b = bh >> 3, h = bh & 7;
    const int tid = threadIdx.x;
    const int w = tid >> 6, lane = tid & 63;
    const int quad = lane >> 4, l16 = lane & 15;
    const int mrow0 = 32 * w;

    for (int idx = tid; idx < 96 * 64; idx += 256) {
        int d = idx >> 6, s = idx & 63;
        ushort_t val = 0;
        if (s < SEQ) val = v[(size_t)(b * SEQ + s) * D_MODEL + h * HDIM + d];
        Vt[d][s] = val;
    }

    f32x4 accS[2][4];
#pragma unroll
    for (int i = 0; i < 2; i++)
#pragma unroll
        for (int j = 0; j < 4; j++) accS[i][j] = (f32x4){0.f, 0.f, 0.f, 0.f};

#pragma unroll
    for (int k0 = 0; k0 < HDIM; k0 += 32) {
        short8 af[2], bfr[4];
#pragma unroll
        for (int mt = 0; mt < 2; mt++) {
            int kq = min(mrow0 + mt * 16 + l16, KQ - 1);
            af[mt] = *(const short8*)(q + (size_t)kq * D_MODEL + h * HDIM + k0 + quad * 8);
        }
#pragma unroll
        for (int nt = 0; nt < 4; nt++) {
            int s = min(nt * 16 + l16, SEQ - 1);
            bfr[nt] = *(const short8*)(k + (size_t)(b * SEQ + s) * D_MODEL + h * HDIM + k0 + quad * 8);
        }
#pragma unroll
        for (int mt = 0; mt < 2; mt++)
#pragma unroll
            for (int nt = 0; nt < 4; nt++)
                accS[mt][nt] = __builtin_amdgcn_mfma_f32_16x16x32_bf16(
                    af[mt], bfr[nt], accS[mt][nt], 0, 0, 0);
    }

#pragma unroll
    for (int mt = 0; mt < 2; mt++) {
#pragma unroll
        for (int r = 0; r < 4; r++) {
            float vals[4];
            float vmax = -1e30f;
#pragma unroll
            for (int nt = 0; nt < 4; nt++) {
                vals[nt] = accS[mt][nt][r];
                if (nt * 16 + l16 < SEQ) vmax = fmaxf(vmax, vals[nt]);
            }
#pragma unroll
            for (int off = 1; off < 16; off <<= 1)
                vmax = fmaxf(vmax, __shfl_xor(vmax, off));
            float p[4], psum = 0.f;
#pragma unroll
            for (int nt = 0; nt < 4; nt++) {
                float e = (nt * 16 + l16 < SEQ) ? __expf(vals[nt] - vmax) : 0.f;
                p[nt] = e;
                psum += e;
            }
#pragma unroll
            for (int off = 1; off < 16; off <<= 1)
                psum += __shfl_xor(psum, off);
            const float inv = 1.f / psum;
            const int row = mrow0 + mt * 16 + quad * 4 + r;
#pragma unroll
            for (int nt = 0; nt < 4; nt++)
                Pt[row][nt * 16 + l16] = f2bf(p[nt] * inv);
        }
    }
    __syncthreads();

    f32x4 accO[2][6];
#pragma unroll
    for (int i = 0; i < 2; i++)
#pragma unroll
        for (int j = 0; j < 6; j++) accO[i][j] = (f32x4){0.f, 0.f, 0.f, 0.f};

#pragma unroll
    for (int k0 = 0; k0 < 64; k0 += 32) {
        short8 af[2], bfr[6];
#pragma unroll
        for (int mt = 0; mt < 2; mt++)
            af[mt] = *(const short8*)(&Pt[mrow0 + mt * 16 + l16][k0 + quad * 8]);
#pragma unroll
        for (int nt = 0; nt < 6; nt++)
            bfr[nt] = *(const short8*)(&Vt[nt * 16 + l16][k0 + quad * 8]);
#pragma unroll
        for (int mt = 0; mt < 2; mt++)
#pragma unroll
            for (int nt = 0; nt < 6; nt++)
                accO[mt][nt] = __builtin_amdgcn_mfma_f32_16x16x32_bf16(
                    af[mt], bfr[nt], accO[mt][nt], 0, 0, 0);
    }

#pragma unroll
    for (int mt = 0; mt < 2; mt++) {
#pragma unroll
        for (int r = 0; r < 4; r++) {
            const int kq = mrow0 + mt * 16 + quad * 4 + r;
            if (kq < KQ) {
                size_t oa = (size_t)(b * KQ + kq) * D_MODEL + h * HDIM;
#pragma unroll
                for (int nt = 0; nt < 6; nt++)
                    ctx[oa + nt * 16 + l16] = f2bf(accO[mt][nt][r]);
            }
        }
    }
}

// ---------------------------------------------------------------------------
// GroupFC + fused LN3.  Block = (bgroup of 8 batches, kq).  (verified R7)
// ---------------------------------------------------------------------------
__global__ __launch_bounds__(256) void groupfc3(
    const ushort_t* __restrict__ hb, const float* __restrict__ dp,
    const float* __restrict__ dbias, const float* __restrict__ g3,
    const float* __restrict__ be3, float* __restrict__ out)
{
    __shared__ float dps[D_MODEL * 11];   // [d][g] padded
    __shared__ float hsr[8][D_MODEL];
    __shared__ float gbs[2][D_MODEL];

    const int b0 = blockIdx.x * 8;
    const int kq = blockIdx.y;
    const int tid = threadIdx.x;

    for (int i = tid; i < D_MODEL * GRP; i += 256) {
        int d = i / GRP, g = i - d * GRP;
        dps[d * 11 + g] = dp[(size_t)kq * (D_MODEL * GRP) + i];
    }
    for (int i = tid; i < D_MODEL; i += 256) {
        gbs[0][i] = g3[i];
        gbs[1][i] = be3[i];
    }
#pragma unroll
    for (int bb = 0; bb < 8; bb++) {
#pragma unroll
        for (int i = 0; i < 3; i++) {
            int d = tid + i * 256;
            hsr[bb][d] = bf2f(hb[(size_t)((b0 + bb) * KQ + kq) * D_MODEL + d]);
        }
    }
    __syncthreads();

    const int w = tid >> 6, lane = tid & 63;

#pragma unroll
    for (int rr = 0; rr < 2; rr++) {
        const int r = w * 2 + rr;
        float v[12];
        float s = 0.f;
#pragma unroll
        for (int i = 0; i < 12; i++) { v[i] = hsr[r][lane + i * 64]; s += v[i]; }
#pragma unroll
        for (int off = 32; off > 0; off >>= 1) s += __shfl_xor(s, off);
        const float mean = s * (1.f / D_MODEL);
        float q = 0.f;
#pragma unroll
        for (int i = 0; i < 12; i++) { float d = v[i] - mean; q += d * d; }
#pragma unroll
        for (int off = 32; off > 0; off >>= 1) q += __shfl_xor(q, off);
        const float rstd = rsqrtf(q * (1.f / D_MODEL) + 1e-5f);
#pragma unroll
        for (int i = 0; i < 12; i++) {
            int d = lane + i * 64;
            hsr[r][d] = (v[i] - mean) * rstd * gbs[0][d] + gbs[1][d];
        }
    }
    __syncthreads();

    for (int item = w; item < 8 * GRP; item += 4) {
        int bb = item / GRP, g = item - bb * GRP;
        float a = 0.f;
#pragma unroll
        for (int i = 0; i < 12; i++) {
            int d = lane + i * 64;
            a = fmaf(hsr[bb][d], dps[d * 11 + g], a);
        }
#pragma unroll
        for (int off = 32; off > 0; off >>= 1) a += __shfl_down(a, off);
        if (lane == 0)
            out[(size_t)(b0 + bb) * NCLS + kq * GRP + g] = a + dbias[kq * GRP + g];
    }
}

// ---------------------------------------------------------------------------
extern "C" void kernel_launch(void* const* d_in, const int* in_sizes, int n_in,
                              void* d_out, int out_size, void* d_ws, size_t ws_size,
                              hipStream_t stream)
{
    const float* x   = (const float*)d_in[0];
    const float* We  = (const float*)d_in[1];
    const float* be_ = (const float*)d_in[2];
    const float* qe  = (const float*)d_in[3];
    const float* wq  = (const float*)d_in[4];
    const float* wk  = (const float*)d_in[5];
    const float* wv  = (const float*)d_in[6];
    const float* bq  = (const float*)d_in[7];
    const float* bk  = (const float*)d_in[8];
    const float* bv  = (const float*)d_in[9];
    const float* wo  = (const float*)d_in[10];
    const float* bo  = (const float*)d_in[11];
    const float* w1  = (const float*)d_in[12];
    const float* b1  = (const float*)d_in[13];
    const float* w2  = (const float*)d_in[14];
    const float* b2  = (const float*)d_in[15];
    const float* g1  = (const float*)d_in[16];
    const float* be1 = (const float*)d_in[17];
    const float* g2  = (const float*)d_in[18];
    const float* be2 = (const float*)d_in[19];
    const float* g3  = (const float*)d_in[20];
    const float* be3 = (const float*)d_in[21];
    const float* dp  = (const float*)d_in[22];
    const float* db  = (const float*)d_in[23];
    float* out = (float*)d_out;
    ushort_t* ws = (ushort_t*)d_ws;

    // Workspace (bf16 elems). Region A [0, 27,295,744) time-shared:
    //   phase1: xb | mem | kb | vb     phase2 (>= ffn1): ffh (26,214,400)
    ushort_t* xb  = ws;                      // 6272*2048 = 12,845,056
    ushort_t* mem = xb + 12845056;           // 6272*768  =  4,816,896
    ushort_t* kb  = mem + 4816896;
    ushort_t* vb  = kb + 4816896;
    ushort_t* ffh = ws;                      // 12800*2048 = 26,214,400 (phase2)
    ushort_t* rB  = ws + 27295744;
    ushort_t* Wet = rB;                      // 768*2048 = 1,572,864
    ushort_t* wqt = Wet + 1572864;           // 768*768  =   589,824
    ushort_t* wkt = wqt + 589824;            // wkt/wvt adjacent -> fused kv GEMM
    ushort_t* wvt = wkt + 589824;
    ushort_t* wot = wvt + 589824;
    ushort_t* w1t = wot + 589824;            // 2048*768 = 1,572,864
    ushort_t* w2t = w1t + 1572864;           // 768*2048 = 1,572,864
    ushort_t* tgt = w2t + 1572864;           // 100*768 = 76,800
    ushort_t* qb  = tgt + 76800;
    ushort_t* ctx = qb + 76800;              // 12800*768 = 9,830,400
    ushort_t* t2  = ctx + 9830400;
    ushort_t* hb  = t2 + 9830400;

    dim3 blk(256);
    const float qscale = 1.0f / sqrtf((float)HDIM);

    // 0. prep: 7 weight transposes + x convert, one dispatch
    prep_all<<<dim3(2752), blk, 0, stream>>>(We, wq, wk, wv, wo, w1, w2, x,
                                             Wet, wqt, wkt, wvt, wot, w1t, w2t, xb);

    // 1. mem = relu(xb @ We + b_embed)   [6272 x 768, K=2048]  MT=2 -> 588 blocks
    gemm_bf16<2><<<dim3(6, 98), blk, 0, stream>>>(xb, Wet, be_, be_, mem, mem,
                                                  6272, 768, 2048, 768, 1, 1.f, nullptr, 0);
    // 2. tgt = LN(2*qe)                  [100 rows]
    ln4<<<dim3(25), blk, 0, stream>>>(qe, 0, g1, be1, tgt, 2.0f, KQ);
    // 3. qb = (tgt@wq + bq)/sqrt(96)     [100 x 768, K=768]  MT=1 -> 24 blocks
    gemm_bf16<1><<<dim3(6, 4), blk, 0, stream>>>(tgt, wqt, bq, bq, qb, qb,
                                                 KQ, 768, 768, 768, 0, qscale, nullptr, 0);
    // 4. fused k|v                       [6272 x 1536, K=768]  MT=2 -> 1176 blocks
    gemm_bf16<2><<<dim3(12, 98), blk, 0, stream>>>(mem, wkt, bk, bv, kb, vb,
                                                   6272, 1536, 768, 768, 0, 1.f, nullptr, 0);
    // 5. attention -> ctx
    attn_mfma<<<dim3(NB * HEADS), blk, 0, stream>>>(qb, kb, vb, ctx);
    // 6. t2 = ctx@wo + bo + bcast tgt    [12800 x 768, K=768]  MT=2 -> 1200 blocks
    gemm_bf16<2><<<dim3(6, 200), blk, 0, stream>>>(ctx, wot, bo, bo, t2, t2,
                                                   12800, 768, 768, 768, 0, 1.f, tgt, 2);
    // 7. t2 = LN(t2)                     [12800 rows]
    ln4<<<dim3(3200), blk, 0, stream>>>(t2, 1, g2, be2, t2, 1.0f, 12800);
    // 8. ffh = relu(t2@w1 + b1)          [12800 x 2048, K=768]  MT=2 -> 3200 blocks
    gemm_bf16<2><<<dim3(16, 200), blk, 0, stream>>>(t2, w1t, b1, b1, ffh, ffh,
                                                    12800, 2048, 768, 2048, 1, 1.f, nullptr, 0);
    // 9. hb = ffh@w2 + b2 + t2           [12800 x 768, K=2048]  MT=2 -> 1200 blocks
    gemm_bf16<2><<<dim3(6, 200), blk, 0, stream>>>(ffh, w2t, b2, b2, hb, hb,
                                                   12800, 768, 2048, 768, 0, 1.f, t2, 1);
    // 10. GroupFC with fused LN3 -> out (fp32 logits)
    groupfc3<<<dim3(16, KQ), blk, 0, stream>>>(hb, dp, db, g3, be3, out);
}